// Round 14
// baseline (225.365 us; speedup 1.0000x reference)
//
#include <hip/hip_runtime.h>
#include <math.h>

constexpr int B_   = 2;
constexpr int T_   = 2048;
constexpr int C_   = 512;
constexpr int H_   = 8;
constexpr int HD_  = 64;
constexpr int M_   = B_ * T_;     // 4096
constexpr int FF_  = 4 * C_;      // 2048
constexpr int NQKV_ = 3 * C_;     // 1536

typedef __attribute__((ext_vector_type(8))) short short8;
typedef __attribute__((ext_vector_type(4))) short short4v;
typedef __attribute__((ext_vector_type(4))) float floatx4;

static __device__ __forceinline__ unsigned short f2bf(float f) {
    union { float f; unsigned u; } v; v.f = f;
    unsigned r = v.u + 0x7fff + ((v.u >> 16) & 1);   // RNE; inputs finite
    return (unsigned short)(r >> 16);
}

static __device__ __forceinline__ float bf2f(unsigned short s) {
    union { unsigned u; float f; } v; v.u = (unsigned)s << 16; return v.f;
}

// pack two floats to bf16x2 dword (RNE)
static __device__ __forceinline__ unsigned packbf2(float a, float b) {
    union { float f; unsigned u; } x, y; x.f = a; y.f = b;
    unsigned lo = (x.u + 0x7fff + ((x.u >> 16) & 1)) >> 16;
    unsigned hi = (y.u + 0x7fff + ((y.u >> 16) & 1)) & 0xffff0000u;
    return lo | hi;
}

// async global->LDS, 16B per lane. LDS dest must be wave-uniform base + lane*16.
static __device__ __forceinline__ void gl2lds16(const unsigned short* g,
                                                unsigned short* l) {
    __builtin_amdgcn_global_load_lds(
        (const __attribute__((address_space(1))) void*)g,
        (__attribute__((address_space(3))) void*)l, 16, 0, 0);
}

// 16x16x16 bf16 MFMA (K=16): A/B = 4 bf16 per lane at [dim=lane&15][k=quad*4+r]
#if __has_builtin(__builtin_amdgcn_mfma_f32_16x16x16bf16_1k)
static __device__ __forceinline__ floatx4 mfma16(short4v a, short4v b, floatx4 c) {
    return __builtin_amdgcn_mfma_f32_16x16x16bf16_1k(a, b, c, 0, 0, 0);
}
#elif __has_builtin(__builtin_amdgcn_mfma_f32_16x16x16_bf16)
static __device__ __forceinline__ floatx4 mfma16(short4v a, short4v b, floatx4 c) {
    return __builtin_amdgcn_mfma_f32_16x16x16_bf16(a, b, c, 0, 0, 0);
}
#else
static __device__ __forceinline__ floatx4 mfma16(short4v a, short4v b, floatx4 c) {
    asm volatile("v_mfma_f32_16x16x16_bf16 %0, %1, %2, %0"
                 : "+v"(c) : "v"(a), "v"(b));
    return c;
}
#endif

// ---------------------------------------------------------------------------
// LayerNorm row helper: one wave handles one row of C=512, bf16 output
// ---------------------------------------------------------------------------
static __device__ __forceinline__ void ln_row(int row, int lane,
                                              const float* __restrict__ x,
                                              const float* __restrict__ g,
                                              const float* __restrict__ b,
                                              unsigned short* __restrict__ out) {
    const float* xr = x + (size_t)row * C_;
    int c0 = lane * 8;
    float4 v0 = *(const float4*)(xr + c0);
    float4 v1 = *(const float4*)(xr + c0 + 4);
    float vals[8] = {v0.x, v0.y, v0.z, v0.w, v1.x, v1.y, v1.z, v1.w};

    float s = 0.f, ss = 0.f;
#pragma unroll
    for (int j = 0; j < 8; j++) { s += vals[j]; ss += vals[j] * vals[j]; }
#pragma unroll
    for (int off = 32; off; off >>= 1) {
        s  += __shfl_xor(s,  off);
        ss += __shfl_xor(ss, off);
    }
    float mu  = s / C_;
    float var = ss / C_ - mu * mu;
    float rs  = rsqrtf(var + 1e-5f);

    unsigned short* orow = out + (size_t)row * C_;
#pragma unroll
    for (int j = 0; j < 8; j++) {
        int c = c0 + j;
        orow[c] = f2bf((vals[j] - mu) * rs * g[c] + b[c]);
    }
}

// ---------------------------------------------------------------------------
// Prologue: weight prep (blocks [0,3072)) + LN1 (blocks [3072,4096), 4 rows ea)
// ---------------------------------------------------------------------------
__global__ __launch_bounds__(256) void prologue(
        const float* __restrict__ Wq, const float* __restrict__ Wk,
        const float* __restrict__ Wv, const float* __restrict__ Wo,
        const float* __restrict__ W1, const float* __restrict__ W2,
        const float* __restrict__ x,  const float* __restrict__ g1,
        const float* __restrict__ be1,
        unsigned short* __restrict__ Wqkv_t, unsigned short* __restrict__ Wo_t,
        unsigned short* __restrict__ W1_t,   unsigned short* __restrict__ W2_t,
        unsigned short* __restrict__ hb) {
    int idx = blockIdx.x;
    int tid = threadIdx.x;
    if (idx >= 3072) {                           // LN1: 4 rows per block
        int row = (idx - 3072) * 4 + (tid >> 6);
        ln_row(row, tid & 63, x, g1, be1, hb);
        return;
    }
    __shared__ float tile[32][33];
    const float* src; unsigned short* dst;
    int K, N, k0, n0;
    float scale = 1.0f;
    if (idx < 768) {
        int wz = idx >> 8, rem = idx & 255;
        int h = rem >> 5, r2 = rem & 31;
        k0 = (r2 >> 1) * 32; n0 = (r2 & 1) * 32;
        src = (wz == 0 ? Wq : (wz == 1 ? Wk : Wv)) + (size_t)h * C_ * HD_;
        dst = Wqkv_t + (size_t)(wz * C_ + h * HD_) * C_;
        K = C_; N = HD_;
        if (wz == 0) scale = 0.125f;             // fold HD^-0.5 into Wq
    } else if (idx < 1024) {
        int rem = idx - 768;
        n0 = (rem & 15) * 32; k0 = (rem >> 4) * 32;
        src = Wo; dst = Wo_t; K = C_; N = C_;
    } else if (idx < 2048) {
        int rem = idx - 1024;
        n0 = (rem & 63) * 32; k0 = (rem >> 6) * 32;
        src = W1; dst = W1_t; K = C_; N = FF_;
    } else {
        int rem = idx - 2048;
        n0 = (rem & 15) * 32; k0 = (rem >> 4) * 32;
        src = W2; dst = W2_t; K = FF_; N = C_;
    }
    int tx = tid & 31, ty = tid >> 5;            // 32 x 8
#pragma unroll
    for (int i = 0; i < 4; i++)
        tile[ty + i * 8][tx] = src[(size_t)(k0 + ty + i * 8) * N + n0 + tx];
    __syncthreads();
#pragma unroll
    for (int i = 0; i < 4; i++)
        dst[(size_t)(n0 + ty + i * 8) * K + k0 + tx] = f2bf(tile[tx][ty + i * 8] * scale);
}

// ---------------------------------------------------------------------------
// LayerNorm standalone (LN2): 4 rows per 256-thread block
// ---------------------------------------------------------------------------
__global__ __launch_bounds__(256) void ln_kernel(
        const float* __restrict__ x, const float* __restrict__ g,
        const float* __restrict__ b, unsigned short* __restrict__ out) {
    int tid = threadIdx.x;
    int row = blockIdx.x * 4 + (tid >> 6);
    ln_row(row, tid & 63, x, g, b, out);
}

// ---------------------------------------------------------------------------
// bf16 MFMA GEMM, templated tile + FLAGS: C[MxN] = A[MxK] @ Bt[NxK]^T
// FLAGS: 1=bias, 2=resid(fp32), 4=gelu, 8=bf16 out (else fp32 out),
//        16=V-transpose epilogue (QKV: n0>=2C writes vT[bh][d][t]),
//        32=A-combine staging: A = (oP0+oP1)/(l0+l1) from attention partials,
//        128=A-DIRECT: A-fragments loaded global->VGPR (no A LDS staging).
//        A-direct loads are issued alongside B's global_load_lds; the staging
//        barrier's vmcnt(0) drain makes both visible together (no extra cost).
// ---------------------------------------------------------------------------
template<int BM, int BN, int BK, int FLAGS>
__global__ __launch_bounds__(256) void mfma_gemm(
        const unsigned short* __restrict__ A,
        const unsigned short* __restrict__ Bt,
        const float* __restrict__ bias,
        const float* __restrict__ resid,
        float* __restrict__ outF,
        unsigned short* __restrict__ outB,
        unsigned short* __restrict__ vT,
        const float* __restrict__ lP,
        int M, int N, int K) {
    constexpr int WM = BM / 2, WN = BN / 2;
    constexpr int MI = WM / 16, NI = WN / 16, KH = BK / 32;
    constexpr bool ADIR = (FLAGS & 128) != 0;
    constexpr int ASH = ADIR ? 0 : KH * BM * 32;     // A LDS shorts
    constexpr int BSH = KH * BN * 32;                // B LDS shorts
    constexpr int TSH = (FLAGS & 16) ? BN * 72 : 0;  // V-transpose scratch
    constexpr int SM  = (ASH + BSH) > TSH ? (ASH + BSH) : TSH;
    __shared__ unsigned short smem[SM];
    unsigned short* As = smem;
    unsigned short* Bs = smem + ASH;

    int t = threadIdx.x;
    int lane = t & 63, w = t >> 6;
    int wr = (w >> 1) * WM, wc = (w & 1) * WN;
    int lm = lane & 15, lq = lane >> 4;
    int m0 = blockIdx.y * BM, n0 = blockIdx.x * BN;

    floatx4 acc[MI][NI];
#pragma unroll
    for (int mi = 0; mi < MI; mi++)
#pragma unroll
        for (int ni = 0; ni < NI; ni++) acc[mi][ni] = (floatx4){0.f, 0.f, 0.f, 0.f};

    for (int k0 = 0; k0 < K; k0 += BK) {
        __syncthreads();
        short8 afr[KH][MI];
        if constexpr (ADIR) {
            // A-fragments direct from global (lane pattern proven in attention)
#pragma unroll
            for (int hh = 0; hh < KH; hh++)
#pragma unroll
                for (int mi = 0; mi < MI; mi++)
                    afr[hh][mi] = *(const short8*)(
                        A + (size_t)(m0 + wr + mi * 16 + lm) * K + k0 + hh * 32 + lq * 8);
        } else if constexpr ((FLAGS & 32) != 0) {
            // A = combined attention partials, normalized, staged via VGPRs
#pragma unroll
            for (int hh = 0; hh < KH; hh++) {
#pragma unroll
                for (int j = 0; j < BM * 4 / 256; j++) {
                    int i = t + j * 256;
                    int gr = m0 + (i >> 2);
                    int f = k0 + hh * 32 + (i & 3) * 8;
                    const unsigned short* pa = A + (size_t)gr * K + f;
                    short8 a8 = *(const short8*)pa;
                    short8 b8 = *(const short8*)(pa + (size_t)M_ * C_);
                    float l0 = lP[(size_t)gr * H_ + (f >> 6)];
                    float l1 = lP[(size_t)(M_ + gr) * H_ + (f >> 6)];
                    float inv = 1.f / (l0 + l1);
                    unsigned pk[4];
#pragma unroll
                    for (int q = 0; q < 4; q++) {
                        float v0 = (bf2f((unsigned short)a8[2 * q]) +
                                    bf2f((unsigned short)b8[2 * q])) * inv;
                        float v1 = (bf2f((unsigned short)a8[2 * q + 1]) +
                                    bf2f((unsigned short)b8[2 * q + 1])) * inv;
                        pk[q] = packbf2(v0, v1);
                    }
                    *(short8*)&As[hh * BM * 32 + i * 8] = *(short8*)pk;
                }
            }
        } else {
#pragma unroll
            for (int hh = 0; hh < KH; hh++)
#pragma unroll
                for (int j = 0; j < BM * 4 / 256; j++) {
                    int i = t + j * 256;
                    gl2lds16(A + (size_t)(m0 + (i >> 2)) * K + k0 + hh * 32 + (i & 3) * 8,
                             &As[hh * BM * 32 + i * 8]);
                }
        }
#pragma unroll
        for (int hh = 0; hh < KH; hh++)
#pragma unroll
            for (int j = 0; j < BN * 4 / 256; j++) {
                int i = t + j * 256;
                gl2lds16(Bt + (size_t)(n0 + (i >> 2)) * K + k0 + hh * 32 + (i & 3) * 8,
                         &Bs[hh * BN * 32 + i * 8]);
            }
        __syncthreads();   // vmcnt(0) drain: B LDS + A-direct VGPRs both ready

#pragma unroll
        for (int hh = 0; hh < KH; hh++) {
            short8 af[MI], bfv[NI];
#pragma unroll
            for (int mi = 0; mi < MI; mi++) {
                if constexpr (ADIR)
                    af[mi] = afr[hh][mi];
                else
                    af[mi] = *(const short8*)&As[hh * BM * 32 + (wr + mi * 16 + lm) * 32 + lq * 8];
            }
#pragma unroll
            for (int ni = 0; ni < NI; ni++)
                bfv[ni] = *(const short8*)&Bs[hh * BN * 32 + (wc + ni * 16 + lm) * 32 + lq * 8];
#pragma unroll
            for (int mi = 0; mi < MI; mi++)
#pragma unroll
                for (int ni = 0; ni < NI; ni++)
                    acc[mi][ni] = __builtin_amdgcn_mfma_f32_16x16x32_bf16(
                        af[mi], bfv[ni], acc[mi][ni], 0, 0, 0);
        }
    }

    // V-transpose epilogue (block-uniform branch, QKV only)
    if constexpr ((FLAGS & 16) != 0) {
        if (n0 >= 2 * C_) {
            __syncthreads();
            unsigned short* Ts = smem;           // [BN][72] bf16
#pragma unroll
            for (int mi = 0; mi < MI; mi++)
#pragma unroll
                for (int ni = 0; ni < NI; ni++) {
                    int cl = wc + ni * 16 + lm;
#pragma unroll
                    for (int r = 0; r < 4; r++)
                        Ts[cl * 72 + wr + mi * 16 + lq * 4 + r] = f2bf(acc[mi][ni][r]);
                }
            __syncthreads();
            int b = m0 >> 11, trow = m0 & (T_ - 1);
#pragma unroll
            for (int it = 0; it < BN * (BM / 8) / 256; it++) {
                int u = it * 256 + t;
                int cl = u >> 3, seg = u & 7;
                int vcol = n0 - 2 * C_ + cl;
                int hh2 = vcol >> 6, dd = vcol & 63;
                short8 vv = *(const short8*)&Ts[cl * 72 + seg * 8];
                *(short8*)&vT[(size_t)((b * H_ + hh2) * HD_ + dd) * T_ + trow + seg * 8] = vv;
            }
            return;
        }
    }

#pragma unroll
    for (int mi = 0; mi < MI; mi++)
#pragma unroll
        for (int ni = 0; ni < NI; ni++) {
            int gc = n0 + wc + ni * 16 + lm;
#pragma unroll
            for (int r = 0; r < 4; r++) {
                int gr = m0 + wr + mi * 16 + lq * 4 + r;
                float v = acc[mi][ni][r];
                if constexpr ((FLAGS & 1) != 0) v += bias[gc];
                if constexpr ((FLAGS & 4) != 0)
                    v = 0.5f * v * (1.0f + erff(v * 0.70710678118654752f));
                if constexpr ((FLAGS & 2) != 0) v += resid[(size_t)gr * N + gc];
                if constexpr ((FLAGS & 8) != 0) outB[(size_t)gr * N + gc] = f2bf(v);
                else                            outF[(size_t)gr * N + gc] = v;
            }
        }
}

// ---------------------------------------------------------------------------
// MFMA flash attention v5 (causal, no-max softmax; S^T formulation).
// Single-buffered K/V LDS (18 KB) -> 6 blocks/CU; register prefetch of next
// chunk overlaps compute. Key-parity split partials (oP bf16, lP fp32).
// ---------------------------------------------------------------------------
__global__ __launch_bounds__(256, 6) void attn_mfma(
        const unsigned short* __restrict__ qkv,
        const unsigned short* __restrict__ vT,
        unsigned short* __restrict__ oP,
        float* __restrict__ lP) {
    __shared__ unsigned short Ks[64 * 72];       // [key][d], pad 72
    __shared__ unsigned short Vt[64 * 72];       // [d][key], pad 72

    int t = threadIdx.x;
    int wq = t >> 6, lane = t & 63;
    int lm = lane & 15, quad = lane >> 4;
    int bh = blockIdx.y, b = bh >> 3, h = bh & 7;
    int tile = blockIdx.x >> 1, s = blockIdx.x & 1;
    int q0 = tile * 64;

    int srow = t >> 2, sq4 = t & 3;

    const unsigned short* kbase = qkv + (size_t)(b * T_) * NQKV_ + C_ + h * HD_;
    const unsigned short* vbase = vT + (size_t)(bh * HD_ + srow) * T_;

    int gq_row = q0 + wq * 16 + lm;
    const unsigned short* qp = qkv + (size_t)(b * T_ + gq_row) * NQKV_ + h * HD_;
    short8 qf0 = *(const short8*)(qp + quad * 8);
    short8 qf1 = *(const short8*)(qp + 32 + quad * 8);

    float l_s = 0.f;
    floatx4 o_acc[4];
#pragma unroll
    for (int dt = 0; dt < 4; dt++) o_acc[dt] = (floatx4){0.f, 0.f, 0.f, 0.f};

    short8 kp0, kp1, vp0, vp1;
    if (s <= tile) {                             // prefetch chunk s
        int s0 = s * 64;
        const unsigned short* kg = kbase + (size_t)(s0 + srow) * NQKV_ + sq4 * 16;
        kp0 = *(const short8*)kg;
        kp1 = *(const short8*)(kg + 8);
        vp0 = *(const short8*)(vbase + s0 + sq4 * 16);
        vp1 = *(const short8*)(vbase + s0 + sq4 * 16 + 8);
    }

    for (int c = s; c <= tile; c += 2) {
        __syncthreads();   // previous chunk's LDS readers done
        *(short8*)&Ks[srow * 72 + sq4 * 16]     = kp0;
        *(short8*)&Ks[srow * 72 + sq4 * 16 + 8] = kp1;
        *(short8*)&Vt[srow * 72 + sq4 * 16]     = vp0;
        *(short8*)&Vt[srow * 72 + sq4 * 16 + 8] = vp1;
        // issue next chunk's global loads; latency overlaps compute below
        if (c + 2 <= tile) {
            int s0n = (c + 2) * 64;
            const unsigned short* kgn = kbase + (size_t)(s0n + srow) * NQKV_ + sq4 * 16;
            kp0 = *(const short8*)kgn;
            kp1 = *(const short8*)(kgn + 8);
            vp0 = *(const short8*)(vbase + s0n + sq4 * 16);
            vp1 = *(const short8*)(vbase + s0n + sq4 * 16 + 8);
        }
        __syncthreads();   // staged chunk visible

        bool diag = (c == tile);
#pragma unroll
        for (int kt = 0; kt < 4; kt++) {
            if (diag && kt > wq) continue;
            short8 kf0 = *(const short8*)&Ks[(kt * 16 + lm) * 72 + quad * 8];
            short8 kf1 = *(const short8*)&Ks[(kt * 16 + lm) * 72 + 32 + quad * 8];
            floatx4 sv = (floatx4){0.f, 0.f, 0.f, 0.f};
            sv = __builtin_amdgcn_mfma_f32_16x16x32_bf16(kf0, qf0, sv, 0, 0, 0);
            sv = __builtin_amdgcn_mfma_f32_16x16x32_bf16(kf1, qf1, sv, 0, 0, 0);
            float p0, p1, p2, p3;
            {
                bool e = diag && (kt == wq);
                p0 = (e && (quad * 4 + 0 > lm)) ? 0.f : __expf(sv[0]);
                p1 = (e && (quad * 4 + 1 > lm)) ? 0.f : __expf(sv[1]);
                p2 = (e && (quad * 4 + 2 > lm)) ? 0.f : __expf(sv[2]);
                p3 = (e && (quad * 4 + 3 > lm)) ? 0.f : __expf(sv[3]);
            }
            l_s += (p0 + p1) + (p2 + p3);
            uint2 pu;
            pu.x = packbf2(p0, p1);
            pu.y = packbf2(p2, p3);
            short4v pk = *(short4v*)&pu;
#pragma unroll
            for (int dt = 0; dt < 4; dt++) {
                short4v vf = *(const short4v*)&Vt[(dt * 16 + lm) * 72 + kt * 16 + quad * 4];
                o_acc[dt] = mfma16(pk, vf, o_acc[dt]);
            }
        }
    }

    // epilogue: write UNNORMALIZED bf16 partials (zero if no work this parity)
    float lsum = l_s;
    lsum += __shfl_xor(lsum, 16);
    lsum += __shfl_xor(lsum, 32);
    if (quad == 0)
        lP[(size_t)s * M_ * H_ + (size_t)(b * T_ + q0 + wq * 16 + lm) * H_ + h] = lsum;
    unsigned short* obase = oP + (size_t)s * M_ * C_;
#pragma unroll
    for (int r = 0; r < 4; r++) {
        int gq = q0 + wq * 16 + quad * 4 + r;
        unsigned short* op = obase + (size_t)(b * T_ + gq) * C_ + h * HD_ + lm;
#pragma unroll
        for (int dt = 0; dt < 4; dt++)
            op[dt * 16] = f2bf(o_acc[dt][r]);
    }
}

// ---------------------------------------------------------------------------
extern "C" void kernel_launch(void* const* d_in, const int* in_sizes, int n_in,
                              void* d_out, int out_size, void* d_ws, size_t ws_size,
                              hipStream_t stream) {
    const float* x   = (const float*)d_in[0];
    const float* Wq  = (const float*)d_in[1];
    const float* Wk  = (const float*)d_in[2];
    const float* Wv  = (const float*)d_in[3];
    const float* Wo  = (const float*)d_in[4];
    const float* bo  = (const float*)d_in[5];
    const float* W1  = (const float*)d_in[6];
    const float* b1  = (const float*)d_in[7];
    const float* W2  = (const float*)d_in[8];
    const float* b2  = (const float*)d_in[9];
    const float* g1  = (const float*)d_in[10];
    const float* be1 = (const float*)d_in[11];
    const float* g2  = (const float*)d_in[12];
    const float* be2 = (const float*)d_in[13];
    float* out = (float*)d_out;

    unsigned short* Wqkv_t = (unsigned short*)d_ws;                 // 1536*512
    unsigned short* Wo_t   = Wqkv_t + (size_t)NQKV_ * C_;           // 512*512
    unsigned short* W1_t   = Wo_t   + (size_t)C_ * C_;              // 2048*512
    unsigned short* W2_t   = W1_t   + (size_t)C_ * FF_;             // 512*2048
    unsigned short* hb     = W2_t   + (size_t)FF_ * C_;             // 4096*512
    unsigned short* attnb  = hb     + (size_t)M_ * C_;              // 4096*512 (ff1 alias)
    unsigned short* qkvb   = attnb  + (size_t)M_ * C_;              // 4096*1536
    unsigned short* vTb    = qkvb   + (size_t)M_ * NQKV_;           // 16*64*2048
    unsigned short* oPb    = vTb    + (size_t)M_ * C_;              // 2*M*C bf16
    float*          lPf    = (float*)(oPb + 2 * (size_t)M_ * C_);   // 2*M*H fp32
    unsigned short* ff1    = attnb;   // reuses attnb+qkvb (4096*2048)

    // 1. prologue: weight prep + LN1
    prologue<<<4096, 256, 0, stream>>>(Wq, Wk, Wv, Wo, W1, W2, x, g1, be1,
                                       Wqkv_t, Wo_t, W1_t, W2_t, hb);

    // 2. QKV projection -> bf16 (Q,K) + V^T to vTb; A-DIRECT
    mfma_gemm<64, 128, 64, 8 | 16 | 128>
        <<<dim3(NQKV_ / 128, M_ / 64), 256, 0, stream>>>(
        hb, Wqkv_t, nullptr, nullptr, nullptr, qkvb, vTb, nullptr,
        M_, NQKV_, C_);

    // 3. MFMA flash attention v5 (bf16 partials); 1024 blocks, 6/CU
    attn_mfma<<<dim3(64, B_ * H_), 256, 0, stream>>>(qkvb, vTb, oPb, lPf);

    // 4. Wo projection with FUSED partial-combine A-staging (flag 32)
    //    + bias + residual -> out (fp32)
    mfma_gemm<64, 64, 64, 1 | 2 | 32>
        <<<dim3(C_ / 64, M_ / 64), 256, 0, stream>>>(
        oPb, Wo_t, bo, x, out, nullptr, nullptr, lPf, M_, C_, C_);

    // 5. LN2 (4 rows/block)
    ln_kernel<<<M_ / 4, 256, 0, stream>>>(out, g2, be2, hb);

    // 6. FFN1 + bias + GELU (bf16 out); A-DIRECT
    mfma_gemm<64, 128, 64, 1 | 4 | 8 | 128>
        <<<dim3(FF_ / 128, M_ / 64), 256, 0, stream>>>(
        hb, W1_t, b1, nullptr, nullptr, ff1, nullptr, nullptr,
        M_, FF_, C_);

    // 7. FFN2 + bias + residual -> out (fp32); A-DIRECT
    mfma_gemm<64, 64, 64, 1 | 2 | 128>
        <<<dim3(C_ / 64, M_ / 64), 256, 0, stream>>>(
        ff1, W2_t, b2, out, out, nullptr, nullptr, nullptr,
        M_, C_, FF_);
}

// Round 15
// 194.258 us; speedup vs baseline: 1.1601x; 1.1601x over previous
//
#include <hip/hip_runtime.h>
#include <math.h>

constexpr int B_   = 2;
constexpr int T_   = 2048;
constexpr int C_   = 512;
constexpr int H_   = 8;
constexpr int HD_  = 64;
constexpr int M_   = B_ * T_;     // 4096
constexpr int FF_  = 4 * C_;      // 2048
constexpr int NQKV_ = 3 * C_;     // 1536

typedef __attribute__((ext_vector_type(8))) short short8;
typedef __attribute__((ext_vector_type(4))) short short4v;
typedef __attribute__((ext_vector_type(4))) float floatx4;

static __device__ __forceinline__ unsigned short f2bf(float f) {
    union { float f; unsigned u; } v; v.f = f;
    unsigned r = v.u + 0x7fff + ((v.u >> 16) & 1);   // RNE; inputs finite
    return (unsigned short)(r >> 16);
}

static __device__ __forceinline__ float bf2f(unsigned short s) {
    union { unsigned u; float f; } v; v.u = (unsigned)s << 16; return v.f;
}

// pack two floats to bf16x2 dword (RNE)
static __device__ __forceinline__ unsigned packbf2(float a, float b) {
    union { float f; unsigned u; } x, y; x.f = a; y.f = b;
    unsigned lo = (x.u + 0x7fff + ((x.u >> 16) & 1)) >> 16;
    unsigned hi = (y.u + 0x7fff + ((y.u >> 16) & 1)) & 0xffff0000u;
    return lo | hi;
}

// async global->LDS, 16B per lane. LDS dest must be wave-uniform base + lane*16.
static __device__ __forceinline__ void gl2lds16(const unsigned short* g,
                                                unsigned short* l) {
    __builtin_amdgcn_global_load_lds(
        (const __attribute__((address_space(1))) void*)g,
        (__attribute__((address_space(3))) void*)l, 16, 0, 0);
}

// 16x16x16 bf16 MFMA (K=16): A/B = 4 bf16 per lane at [dim=lane&15][k=quad*4+r]
#if __has_builtin(__builtin_amdgcn_mfma_f32_16x16x16bf16_1k)
static __device__ __forceinline__ floatx4 mfma16(short4v a, short4v b, floatx4 c) {
    return __builtin_amdgcn_mfma_f32_16x16x16bf16_1k(a, b, c, 0, 0, 0);
}
#elif __has_builtin(__builtin_amdgcn_mfma_f32_16x16x16_bf16)
static __device__ __forceinline__ floatx4 mfma16(short4v a, short4v b, floatx4 c) {
    return __builtin_amdgcn_mfma_f32_16x16x16_bf16(a, b, c, 0, 0, 0);
}
#else
static __device__ __forceinline__ floatx4 mfma16(short4v a, short4v b, floatx4 c) {
    asm volatile("v_mfma_f32_16x16x16_bf16 %0, %1, %2, %0"
                 : "+v"(c) : "v"(a), "v"(b));
    return c;
}
#endif

// ---------------------------------------------------------------------------
// LayerNorm row helper: one wave handles one row of C=512, bf16 output
// ---------------------------------------------------------------------------
static __device__ __forceinline__ void ln_row(int row, int lane,
                                              const float* __restrict__ x,
                                              const float* __restrict__ g,
                                              const float* __restrict__ b,
                                              unsigned short* __restrict__ out) {
    const float* xr = x + (size_t)row * C_;
    int c0 = lane * 8;
    float4 v0 = *(const float4*)(xr + c0);
    float4 v1 = *(const float4*)(xr + c0 + 4);
    float vals[8] = {v0.x, v0.y, v0.z, v0.w, v1.x, v1.y, v1.z, v1.w};

    float s = 0.f, ss = 0.f;
#pragma unroll
    for (int j = 0; j < 8; j++) { s += vals[j]; ss += vals[j] * vals[j]; }
#pragma unroll
    for (int off = 32; off; off >>= 1) {
        s  += __shfl_xor(s,  off);
        ss += __shfl_xor(ss, off);
    }
    float mu  = s / C_;
    float var = ss / C_ - mu * mu;
    float rs  = rsqrtf(var + 1e-5f);

    unsigned short* orow = out + (size_t)row * C_;
#pragma unroll
    for (int j = 0; j < 8; j++) {
        int c = c0 + j;
        orow[c] = f2bf((vals[j] - mu) * rs * g[c] + b[c]);
    }
}

// ---------------------------------------------------------------------------
// Prologue: weight prep (blocks [0,3072)) + LN1 (blocks [3072,4096), 4 rows ea)
// ---------------------------------------------------------------------------
__global__ __launch_bounds__(256) void prologue(
        const float* __restrict__ Wq, const float* __restrict__ Wk,
        const float* __restrict__ Wv, const float* __restrict__ Wo,
        const float* __restrict__ W1, const float* __restrict__ W2,
        const float* __restrict__ x,  const float* __restrict__ g1,
        const float* __restrict__ be1,
        unsigned short* __restrict__ Wqkv_t, unsigned short* __restrict__ Wo_t,
        unsigned short* __restrict__ W1_t,   unsigned short* __restrict__ W2_t,
        unsigned short* __restrict__ hb) {
    int idx = blockIdx.x;
    int tid = threadIdx.x;
    if (idx >= 3072) {                           // LN1: 4 rows per block
        int row = (idx - 3072) * 4 + (tid >> 6);
        ln_row(row, tid & 63, x, g1, be1, hb);
        return;
    }
    __shared__ float tile[32][33];
    const float* src; unsigned short* dst;
    int K, N, k0, n0;
    float scale = 1.0f;
    if (idx < 768) {
        int wz = idx >> 8, rem = idx & 255;
        int h = rem >> 5, r2 = rem & 31;
        k0 = (r2 >> 1) * 32; n0 = (r2 & 1) * 32;
        src = (wz == 0 ? Wq : (wz == 1 ? Wk : Wv)) + (size_t)h * C_ * HD_;
        dst = Wqkv_t + (size_t)(wz * C_ + h * HD_) * C_;
        K = C_; N = HD_;
        if (wz == 0) scale = 0.125f;             // fold HD^-0.5 into Wq
    } else if (idx < 1024) {
        int rem = idx - 768;
        n0 = (rem & 15) * 32; k0 = (rem >> 4) * 32;
        src = Wo; dst = Wo_t; K = C_; N = C_;
    } else if (idx < 2048) {
        int rem = idx - 1024;
        n0 = (rem & 63) * 32; k0 = (rem >> 6) * 32;
        src = W1; dst = W1_t; K = C_; N = FF_;
    } else {
        int rem = idx - 2048;
        n0 = (rem & 15) * 32; k0 = (rem >> 4) * 32;
        src = W2; dst = W2_t; K = FF_; N = C_;
    }
    int tx = tid & 31, ty = tid >> 5;            // 32 x 8
#pragma unroll
    for (int i = 0; i < 4; i++)
        tile[ty + i * 8][tx] = src[(size_t)(k0 + ty + i * 8) * N + n0 + tx];
    __syncthreads();
#pragma unroll
    for (int i = 0; i < 4; i++)
        dst[(size_t)(n0 + ty + i * 8) * K + k0 + tx] = f2bf(tile[tx][ty + i * 8] * scale);
}

// ---------------------------------------------------------------------------
// LayerNorm standalone (LN2): 4 rows per 256-thread block
// ---------------------------------------------------------------------------
__global__ __launch_bounds__(256) void ln_kernel(
        const float* __restrict__ x, const float* __restrict__ g,
        const float* __restrict__ b, unsigned short* __restrict__ out) {
    int tid = threadIdx.x;
    int row = blockIdx.x * 4 + (tid >> 6);
    ln_row(row, tid & 63, x, g, b, out);
}

// ---------------------------------------------------------------------------
// bf16 MFMA GEMM, templated tile + FLAGS: C[MxN] = A[MxK] @ Bt[NxK]^T
// FLAGS: 1=bias, 2=resid(fp32), 4=gelu, 8=bf16 out (else fp32 out),
//        16=V-transpose epilogue (QKV: n0>=2C writes vT[bh][d][t]),
//        32=A-combine staging: A = (oP0+oP1)/(l0+l1) from attention partials.
// ---------------------------------------------------------------------------
template<int BM, int BN, int BK, int FLAGS>
__global__ __launch_bounds__(256) void mfma_gemm(
        const unsigned short* __restrict__ A,
        const unsigned short* __restrict__ Bt,
        const float* __restrict__ bias,
        const float* __restrict__ resid,
        float* __restrict__ outF,
        unsigned short* __restrict__ outB,
        unsigned short* __restrict__ vT,
        const float* __restrict__ lP,
        int M, int N, int K) {
    constexpr int WM = BM / 2, WN = BN / 2;
    constexpr int MI = WM / 16, NI = WN / 16, KH = BK / 32;
    constexpr int ASH = KH * BM * 32;                // A LDS shorts
    constexpr int BSH = KH * BN * 32;                // B LDS shorts
    constexpr int TSH = (FLAGS & 16) ? BN * 72 : 0;  // V-transpose scratch
    constexpr int SM  = (ASH + BSH) > TSH ? (ASH + BSH) : TSH;
    __shared__ unsigned short smem[SM];
    unsigned short* As = smem;
    unsigned short* Bs = smem + ASH;

    int t = threadIdx.x;
    int lane = t & 63, w = t >> 6;
    int wr = (w >> 1) * WM, wc = (w & 1) * WN;
    int lm = lane & 15, lq = lane >> 4;
    int m0 = blockIdx.y * BM, n0 = blockIdx.x * BN;

    floatx4 acc[MI][NI];
#pragma unroll
    for (int mi = 0; mi < MI; mi++)
#pragma unroll
        for (int ni = 0; ni < NI; ni++) acc[mi][ni] = (floatx4){0.f, 0.f, 0.f, 0.f};

    for (int k0 = 0; k0 < K; k0 += BK) {
        __syncthreads();
        if constexpr ((FLAGS & 32) != 0) {
            // A = combined attention partials, normalized, staged via VGPRs
#pragma unroll
            for (int hh = 0; hh < KH; hh++) {
#pragma unroll
                for (int j = 0; j < BM * 4 / 256; j++) {
                    int i = t + j * 256;
                    int gr = m0 + (i >> 2);
                    int f = k0 + hh * 32 + (i & 3) * 8;
                    const unsigned short* pa = A + (size_t)gr * K + f;
                    short8 a8 = *(const short8*)pa;
                    short8 b8 = *(const short8*)(pa + (size_t)M_ * C_);
                    float l0 = lP[(size_t)gr * H_ + (f >> 6)];
                    float l1 = lP[(size_t)(M_ + gr) * H_ + (f >> 6)];
                    float inv = 1.f / (l0 + l1);
                    unsigned pk[4];
#pragma unroll
                    for (int q = 0; q < 4; q++) {
                        float v0 = (bf2f((unsigned short)a8[2 * q]) +
                                    bf2f((unsigned short)b8[2 * q])) * inv;
                        float v1 = (bf2f((unsigned short)a8[2 * q + 1]) +
                                    bf2f((unsigned short)b8[2 * q + 1])) * inv;
                        pk[q] = packbf2(v0, v1);
                    }
                    *(short8*)&As[hh * BM * 32 + i * 8] = *(short8*)pk;
                }
            }
        } else {
#pragma unroll
            for (int hh = 0; hh < KH; hh++)
#pragma unroll
                for (int j = 0; j < BM * 4 / 256; j++) {
                    int i = t + j * 256;
                    gl2lds16(A + (size_t)(m0 + (i >> 2)) * K + k0 + hh * 32 + (i & 3) * 8,
                             &As[hh * BM * 32 + i * 8]);
                }
        }
#pragma unroll
        for (int hh = 0; hh < KH; hh++)
#pragma unroll
            for (int j = 0; j < BN * 4 / 256; j++) {
                int i = t + j * 256;
                gl2lds16(Bt + (size_t)(n0 + (i >> 2)) * K + k0 + hh * 32 + (i & 3) * 8,
                         &Bs[hh * BN * 32 + i * 8]);
            }
        __syncthreads();   // vmcnt(0) drain: staged data visible

#pragma unroll
        for (int hh = 0; hh < KH; hh++) {
            short8 af[MI], bfv[NI];
#pragma unroll
            for (int mi = 0; mi < MI; mi++)
                af[mi] = *(const short8*)&As[hh * BM * 32 + (wr + mi * 16 + lm) * 32 + lq * 8];
#pragma unroll
            for (int ni = 0; ni < NI; ni++)
                bfv[ni] = *(const short8*)&Bs[hh * BN * 32 + (wc + ni * 16 + lm) * 32 + lq * 8];
#pragma unroll
            for (int mi = 0; mi < MI; mi++)
#pragma unroll
                for (int ni = 0; ni < NI; ni++)
                    acc[mi][ni] = __builtin_amdgcn_mfma_f32_16x16x32_bf16(
                        af[mi], bfv[ni], acc[mi][ni], 0, 0, 0);
        }
    }

    // V-transpose epilogue (block-uniform branch, QKV only)
    if constexpr ((FLAGS & 16) != 0) {
        if (n0 >= 2 * C_) {
            __syncthreads();
            unsigned short* Ts = smem;           // [BN][72] bf16
#pragma unroll
            for (int mi = 0; mi < MI; mi++)
#pragma unroll
                for (int ni = 0; ni < NI; ni++) {
                    int cl = wc + ni * 16 + lm;
#pragma unroll
                    for (int r = 0; r < 4; r++)
                        Ts[cl * 72 + wr + mi * 16 + lq * 4 + r] = f2bf(acc[mi][ni][r]);
                }
            __syncthreads();
            int b = m0 >> 11, trow = m0 & (T_ - 1);
#pragma unroll
            for (int it = 0; it < BN * (BM / 8) / 256; it++) {
                int u = it * 256 + t;
                int cl = u >> 3, seg = u & 7;
                int vcol = n0 - 2 * C_ + cl;
                int hh2 = vcol >> 6, dd = vcol & 63;
                short8 vv = *(const short8*)&Ts[cl * 72 + seg * 8];
                *(short8*)&vT[(size_t)((b * H_ + hh2) * HD_ + dd) * T_ + trow + seg * 8] = vv;
            }
            return;
        }
    }

#pragma unroll
    for (int mi = 0; mi < MI; mi++)
#pragma unroll
        for (int ni = 0; ni < NI; ni++) {
            int gc = n0 + wc + ni * 16 + lm;
#pragma unroll
            for (int r = 0; r < 4; r++) {
                int gr = m0 + wr + mi * 16 + lq * 4 + r;
                float v = acc[mi][ni][r];
                if constexpr ((FLAGS & 1) != 0) v += bias[gc];
                if constexpr ((FLAGS & 4) != 0)
                    v = 0.5f * v * (1.0f + erff(v * 0.70710678118654752f));
                if constexpr ((FLAGS & 2) != 0) v += resid[(size_t)gr * N + gc];
                if constexpr ((FLAGS & 8) != 0) outB[(size_t)gr * N + gc] = f2bf(v);
                else                            outF[(size_t)gr * N + gc] = v;
            }
        }
}

// ---------------------------------------------------------------------------
// MFMA flash attention v5 (causal, no-max softmax; S^T formulation).
// Single-buffered K/V LDS (18 KB) -> 6 blocks/CU; register prefetch of next
// chunk overlaps compute. Key-parity split partials (oP bf16, lP fp32).
// ---------------------------------------------------------------------------
__global__ __launch_bounds__(256, 6) void attn_mfma(
        const unsigned short* __restrict__ qkv,
        const unsigned short* __restrict__ vT,
        unsigned short* __restrict__ oP,
        float* __restrict__ lP) {
    __shared__ unsigned short Ks[64 * 72];       // [key][d], pad 72
    __shared__ unsigned short Vt[64 * 72];       // [d][key], pad 72

    int t = threadIdx.x;
    int wq = t >> 6, lane = t & 63;
    int lm = lane & 15, quad = lane >> 4;
    int bh = blockIdx.y, b = bh >> 3, h = bh & 7;
    int tile = blockIdx.x >> 1, s = blockIdx.x & 1;
    int q0 = tile * 64;

    int srow = t >> 2, sq4 = t & 3;

    const unsigned short* kbase = qkv + (size_t)(b * T_) * NQKV_ + C_ + h * HD_;
    const unsigned short* vbase = vT + (size_t)(bh * HD_ + srow) * T_;

    int gq_row = q0 + wq * 16 + lm;
    const unsigned short* qp = qkv + (size_t)(b * T_ + gq_row) * NQKV_ + h * HD_;
    short8 qf0 = *(const short8*)(qp + quad * 8);
    short8 qf1 = *(const short8*)(qp + 32 + quad * 8);

    float l_s = 0.f;
    floatx4 o_acc[4];
#pragma unroll
    for (int dt = 0; dt < 4; dt++) o_acc[dt] = (floatx4){0.f, 0.f, 0.f, 0.f};

    short8 kp0, kp1, vp0, vp1;
    if (s <= tile) {                             // prefetch chunk s
        int s0 = s * 64;
        const unsigned short* kg = kbase + (size_t)(s0 + srow) * NQKV_ + sq4 * 16;
        kp0 = *(const short8*)kg;
        kp1 = *(const short8*)(kg + 8);
        vp0 = *(const short8*)(vbase + s0 + sq4 * 16);
        vp1 = *(const short8*)(vbase + s0 + sq4 * 16 + 8);
    }

    for (int c = s; c <= tile; c += 2) {
        __syncthreads();   // previous chunk's LDS readers done
        *(short8*)&Ks[srow * 72 + sq4 * 16]     = kp0;
        *(short8*)&Ks[srow * 72 + sq4 * 16 + 8] = kp1;
        *(short8*)&Vt[srow * 72 + sq4 * 16]     = vp0;
        *(short8*)&Vt[srow * 72 + sq4 * 16 + 8] = vp1;
        // issue next chunk's global loads; latency overlaps compute below
        if (c + 2 <= tile) {
            int s0n = (c + 2) * 64;
            const unsigned short* kgn = kbase + (size_t)(s0n + srow) * NQKV_ + sq4 * 16;
            kp0 = *(const short8*)kgn;
            kp1 = *(const short8*)(kgn + 8);
            vp0 = *(const short8*)(vbase + s0n + sq4 * 16);
            vp1 = *(const short8*)(vbase + s0n + sq4 * 16 + 8);
        }
        __syncthreads();   // staged chunk visible

        bool diag = (c == tile);
#pragma unroll
        for (int kt = 0; kt < 4; kt++) {
            if (diag && kt > wq) continue;
            short8 kf0 = *(const short8*)&Ks[(kt * 16 + lm) * 72 + quad * 8];
            short8 kf1 = *(const short8*)&Ks[(kt * 16 + lm) * 72 + 32 + quad * 8];
            floatx4 sv = (floatx4){0.f, 0.f, 0.f, 0.f};
            sv = __builtin_amdgcn_mfma_f32_16x16x32_bf16(kf0, qf0, sv, 0, 0, 0);
            sv = __builtin_amdgcn_mfma_f32_16x16x32_bf16(kf1, qf1, sv, 0, 0, 0);
            float p0, p1, p2, p3;
            {
                bool e = diag && (kt == wq);
                p0 = (e && (quad * 4 + 0 > lm)) ? 0.f : __expf(sv[0]);
                p1 = (e && (quad * 4 + 1 > lm)) ? 0.f : __expf(sv[1]);
                p2 = (e && (quad * 4 + 2 > lm)) ? 0.f : __expf(sv[2]);
                p3 = (e && (quad * 4 + 3 > lm)) ? 0.f : __expf(sv[3]);
            }
            l_s += (p0 + p1) + (p2 + p3);
            uint2 pu;
            pu.x = packbf2(p0, p1);
            pu.y = packbf2(p2, p3);
            short4v pk = *(short4v*)&pu;
#pragma unroll
            for (int dt = 0; dt < 4; dt++) {
                short4v vf = *(const short4v*)&Vt[(dt * 16 + lm) * 72 + kt * 16 + quad * 4];
                o_acc[dt] = mfma16(pk, vf, o_acc[dt]);
            }
        }
    }

    // epilogue: write UNNORMALIZED bf16 partials (zero if no work this parity)
    float lsum = l_s;
    lsum += __shfl_xor(lsum, 16);
    lsum += __shfl_xor(lsum, 32);
    if (quad == 0)
        lP[(size_t)s * M_ * H_ + (size_t)(b * T_ + q0 + wq * 16 + lm) * H_ + h] = lsum;
    unsigned short* obase = oP + (size_t)s * M_ * C_;
#pragma unroll
    for (int r = 0; r < 4; r++) {
        int gq = q0 + wq * 16 + quad * 4 + r;
        unsigned short* op = obase + (size_t)(b * T_ + gq) * C_ + h * HD_ + lm;
#pragma unroll
        for (int dt = 0; dt < 4; dt++)
            op[dt * 16] = f2bf(o_acc[dt][r]);
    }
}

// ---------------------------------------------------------------------------
extern "C" void kernel_launch(void* const* d_in, const int* in_sizes, int n_in,
                              void* d_out, int out_size, void* d_ws, size_t ws_size,
                              hipStream_t stream) {
    const float* x   = (const float*)d_in[0];
    const float* Wq  = (const float*)d_in[1];
    const float* Wk  = (const float*)d_in[2];
    const float* Wv  = (const float*)d_in[3];
    const float* Wo  = (const float*)d_in[4];
    const float* bo  = (const float*)d_in[5];
    const float* W1  = (const float*)d_in[6];
    const float* b1  = (const float*)d_in[7];
    const float* W2  = (const float*)d_in[8];
    const float* b2  = (const float*)d_in[9];
    const float* g1  = (const float*)d_in[10];
    const float* be1 = (const float*)d_in[11];
    const float* g2  = (const float*)d_in[12];
    const float* be2 = (const float*)d_in[13];
    float* out = (float*)d_out;

    unsigned short* Wqkv_t = (unsigned short*)d_ws;                 // 1536*512
    unsigned short* Wo_t   = Wqkv_t + (size_t)NQKV_ * C_;           // 512*512
    unsigned short* W1_t   = Wo_t   + (size_t)C_ * C_;              // 2048*512
    unsigned short* W2_t   = W1_t   + (size_t)C_ * FF_;             // 512*2048
    unsigned short* hb     = W2_t   + (size_t)FF_ * C_;             // 4096*512
    unsigned short* attnb  = hb     + (size_t)M_ * C_;              // 4096*512 (ff1 alias)
    unsigned short* qkvb   = attnb  + (size_t)M_ * C_;              // 4096*1536
    unsigned short* vTb    = qkvb   + (size_t)M_ * NQKV_;           // 16*64*2048
    unsigned short* oPb    = vTb    + (size_t)M_ * C_;              // 2*M*C bf16
    float*          lPf    = (float*)(oPb + 2 * (size_t)M_ * C_);   // 2*M*H fp32
    unsigned short* ff1    = attnb;   // reuses attnb+qkvb (4096*2048)

    // 1. prologue: weight prep + LN1
    prologue<<<4096, 256, 0, stream>>>(Wq, Wk, Wv, Wo, W1, W2, x, g1, be1,
                                       Wqkv_t, Wo_t, W1_t, W2_t, hb);

    // 2. QKV projection -> bf16 (Q,K) + V^T to vTb (LDS-staged A, as R12)
    mfma_gemm<64, 128, 64, 8 | 16>
        <<<dim3(NQKV_ / 128, M_ / 64), 256, 0, stream>>>(
        hb, Wqkv_t, nullptr, nullptr, nullptr, qkvb, vTb, nullptr,
        M_, NQKV_, C_);

    // 3. MFMA flash attention v5 (bf16 partials); 1024 blocks, 6/CU
    attn_mfma<<<dim3(64, B_ * H_), 256, 0, stream>>>(qkvb, vTb, oPb, lPf);

    // 4. Wo projection with FUSED partial-combine A-staging (flag 32)
    //    + bias + residual -> out (fp32)
    mfma_gemm<64, 64, 64, 1 | 2 | 32>
        <<<dim3(C_ / 64, M_ / 64), 256, 0, stream>>>(
        oPb, Wo_t, bo, x, out, nullptr, nullptr, lPf, M_, C_, C_);

    // 5. LN2 (4 rows/block)
    ln_kernel<<<M_ / 4, 256, 0, stream>>>(out, g2, be2, hb);

    // 6. FFN1 + bias + GELU (bf16 out); LDS-staged A (as R12)
    mfma_gemm<64, 128, 64, 1 | 4 | 8>
        <<<dim3(FF_ / 128, M_ / 64), 256, 0, stream>>>(
        hb, W1_t, b1, nullptr, nullptr, ff1, nullptr, nullptr,
        M_, FF_, C_);

    // 7. FFN2 + bias + residual -> out (fp32); BK=128 (16 barrier pairs)
    mfma_gemm<64, 64, 128, 1 | 2>
        <<<dim3(C_ / 64, M_ / 64), 256, 0, stream>>>(
        ff1, W2_t, b2, out, out, nullptr, nullptr, nullptr,
        M_, C_, FF_);
}